// Round 10
// baseline (1790.963 us; speedup 1.0000x reference)
//
#include <hip/hip_runtime.h>
#include <hip/hip_bf16.h>

#define H_DIM 2048
#define I_DIM 4096
#define NE 8
#define NT 1024

// wide-N tiles: W row chunk per block = 256 fp32 = 1KB contiguous
#define BKW 32
#define BN1 256
#define BM1 64
#define BM2 32
#define NS1 (H_DIM / BKW)   // 64
#define NS2 (I_DIM / BKW)   // 128

typedef __bf16 bf16x8 __attribute__((ext_vector_type(8)));
typedef float f32x4 __attribute__((ext_vector_type(4)));
typedef unsigned short u16x8 __attribute__((ext_vector_type(8)));

__device__ __forceinline__ unsigned short f2bf(float f) {
  return __builtin_bit_cast(unsigned short, (__bf16)f);
}
__device__ __forceinline__ float bf2f(unsigned short v) {
  return __builtin_bit_cast(float, (unsigned)v << 16);
}

// async global->LDS, 16B per lane; LDS dest = wave-uniform base + lane*16
__device__ __forceinline__ void gl2lds16(const void* g, void* l) {
  __builtin_amdgcn_global_load_lds(
      (const __attribute__((address_space(1))) unsigned int*)g,
      (__attribute__((address_space(3))) unsigned int*)l, 16, 0, 0);
}

#define FENCE() asm volatile("" ::: "memory")
#define BAR() __builtin_amdgcn_s_barrier()
#define VMC(N) asm volatile("s_waitcnt vmcnt(" #N ")" ::: "memory")
#define SCHED_PIN() __builtin_amdgcn_sched_barrier(0)

// ---------------- router: 1 wave per token ----------------
__global__ __launch_bounds__(256) void router_kernel(
    const float* __restrict__ x, const float* __restrict__ rw,
    float* __restrict__ rs_out, int* __restrict__ expert_of,
    float* __restrict__ score_of, int* __restrict__ counts)
{
  const int lane = threadIdx.x & 63;
  const int wv = threadIdx.x >> 6;
  const int t = blockIdx.x * 4 + wv;
  float acc[NE];
#pragma unroll
  for (int e = 0; e < NE; ++e) acc[e] = 0.f;
  const float* xr = x + (size_t)t * H_DIM;
  for (int h0 = 0; h0 < H_DIM; h0 += 64) {
    const float xv = xr[h0 + lane];
    const float* rwp = rw + (size_t)(h0 + lane) * NE;
    const f32x4 r0 = *(const f32x4*)rwp;
    const f32x4 r1 = *(const f32x4*)(rwp + 4);
#pragma unroll
    for (int e = 0; e < 4; ++e) { acc[e] += xv * r0[e]; acc[e + 4] += xv * r1[e]; }
  }
#pragma unroll
  for (int e = 0; e < NE; ++e) {
    acc[e] += __shfl_xor(acc[e], 32, 64);
    acc[e] += __shfl_xor(acc[e], 16, 64);
    acc[e] += __shfl_xor(acc[e], 8, 64);
    acc[e] += __shfl_xor(acc[e], 4, 64);
    acc[e] += __shfl_xor(acc[e], 2, 64);
    acc[e] += __shfl_xor(acc[e], 1, 64);
  }
  int best = 0; float bv = acc[0];
#pragma unroll
  for (int e = 1; e < NE; ++e) if (acc[e] > bv) { bv = acc[e]; best = e; }
  const float score = 1.f / (1.f + __expf(-bv));
  if (lane < NE) rs_out[(size_t)lane * NT + t] = (lane == best) ? score : 0.f;
  if (lane == 0) {
    expert_of[t] = best;
    score_of[t] = score;
    atomicAdd(&counts[best], 1);
  }
}

// ---------------- offsets ----------------
__global__ void offsets_kernel(const int* __restrict__ counts,
                               int* __restrict__ offsets, int* __restrict__ cursor)
{
  if (threadIdx.x == 0) {
    int run = 0;
#pragma unroll
    for (int e = 0; e < NE; ++e) { offsets[e] = run; run += counts[e]; cursor[e] = 0; }
  }
}

// ---------------- scatter ----------------
__global__ void scatter_kernel(const int* __restrict__ expert_of,
                               const int* __restrict__ offsets,
                               int* __restrict__ cursor, int* __restrict__ perm)
{
  const int t = blockIdx.x * 256 + threadIdx.x;
  const int e = expert_of[t];
  const int p = atomicAdd(&cursor[e], 1);
  perm[offsets[e] + p] = t;
}

// ---------------- gather ----------------
__global__ __launch_bounds__(256) void gather_kernel(
    const float* __restrict__ x, const int* __restrict__ perm,
    const float* __restrict__ score_of, unsigned short* __restrict__ xb,
    unsigned short* __restrict__ xs)
{
  const int b = blockIdx.x;
  const int c = threadIdx.x * 8;
  const int src = perm[b];
  const float s = score_of[src];
  const float* xrow = x + (size_t)b * H_DIM + c;
  const float* srow = x + (size_t)src * H_DIM + c;
  u16x8 vb, vs;
#pragma unroll
  for (int j = 0; j < 8; ++j) {
    vb[j] = f2bf(xrow[j]);
    vs[j] = f2bf(srow[j] * s);
  }
  *(u16x8*)&xb[(size_t)b * H_DIM + c] = vb;
  *(u16x8*)&xs[(size_t)b * H_DIM + c] = vs;
}

// ================= GEMM1-wide: raw = X @ W  (one matrix per block) =================
// W staged via gl2lds: 32 rows x 1KB CONTIGUOUS per K-step (the whole point).
// LDS = 2 x 32KB W only; X lives in a register double-buffer (L2-resident).
// A-frag LDS reads 2-way via XOR-64B swizzle (source pre-swizzled, rule 21).
__global__ __launch_bounds__(256, 2) void gemm1w_kernel(
    const unsigned short* __restrict__ xs, const unsigned short* __restrict__ xb,
    const float* __restrict__ gup, const float* __restrict__ sgw,
    const float* __restrict__ suw, unsigned short* __restrict__ raw_r,
    unsigned short* __restrict__ raw_s, const int* __restrict__ counts,
    const int* __restrict__ offsets)
{
  const int e = blockIdx.z;
  const int y = blockIdx.y;
  int cnt, roff; size_t ldw;
  const unsigned short* X; const float* Wb; unsigned short* OUT; int colout;
  if (e < NE) {
    cnt = counts[e]; roff = offsets[e]; ldw = 2 * I_DIM;
    X = xs; Wb = gup + (size_t)e * H_DIM * 2 * I_DIM + y * BN1;
    OUT = raw_r; colout = y * BN1;
  } else {
    cnt = NT; roff = 0; ldw = I_DIM;
    Wb = (y < 16 ? sgw : suw) + (size_t)(y & 15) * BN1;
    X = xb; OUT = raw_s;
    colout = (y < 16) ? y * BN1 : I_DIM + (y - 16) * BN1;
  }
  const int m0 = blockIdx.x * BM1;
  if (m0 >= cnt) return;

  __shared__ char wl[65536];   // [2][32][1024B]

  const int lane = threadIdx.x & 63, w = threadIdx.x >> 6;

  // W staging: wave w stages rows 8w..8w+7; src chunk pre-swizzled (lane ^ (w<<2))
  const float* wp[8];
#pragma unroll
  for (int s = 0; s < 8; ++s)
    wp[s] = Wb + (size_t)(8 * w + s) * ldw + ((lane ^ (w << 2)) << 2);

#define STAGEW1(CUR) do {                                                \
  _Pragma("unroll")                                                      \
  for (int s = 0; s < 8; ++s) {                                          \
    gl2lds16(wp[s], wl + (CUR) * 32768 + (8 * w + s) * 1024);            \
    wp[s] += (size_t)BKW * ldw;                                          \
  }                                                                      \
} while (0)

  // X register pipeline: per-lane dwordx4 from global (L2-resident)
  const unsigned short* xp[4];
#pragma unroll
  for (int mf = 0; mf < 4; ++mf) {
    const int m = m0 + mf * 16 + (lane & 15);
    xp[mf] = X + (size_t)(m < cnt ? roff + m : roff) * H_DIM + ((lane >> 4) * 8);
  }
#define LOADX1(XR, K0) do {                                              \
  _Pragma("unroll")                                                      \
  for (int mf = 0; mf < 4; ++mf) XR[mf] = *(const u16x8*)(xp[mf] + (K0));\
} while (0)

  // A-frag read bases: k = (lane>>4)*8 + j, n = w*64 + nf*16 + (lane&15)
  // byte = k*1024 + ((n*4) ^ ((lane>>4)<<6))   -> 2-way bank aliasing (free)
  int rb[4];
#pragma unroll
  for (int nf = 0; nf < 4; ++nf)
    rb[nf] = ((lane >> 4) * 8) * 1024 +
             (((w * 64 + nf * 16 + (lane & 15)) * 4) ^ ((lane >> 4) << 6));

  f32x4 acc[4][4] = {};

#define COMP1(CUR, XR) do {                                              \
  const char* _wb = wl + (CUR) * 32768;                                  \
  bf16x8 _af[4];                                                         \
  _Pragma("unroll")                                                      \
  for (int nf = 0; nf < 4; ++nf) {                                       \
    _Pragma("unroll")                                                    \
    for (int j = 0; j < 8; ++j)                                          \
      _af[nf][j] = (__bf16)(*(const float*)(_wb + rb[nf] + j * 1024));   \
  }                                                                      \
  _Pragma("unroll")                                                      \
  for (int mf = 0; mf < 4; ++mf) {                                       \
    const bf16x8 _xf = __builtin_bit_cast(bf16x8, XR[mf]);               \
    _Pragma("unroll")                                                    \
    for (int nf = 0; nf < 4; ++nf)                                       \
      acc[mf][nf] = __builtin_amdgcn_mfma_f32_16x16x32_bf16(_af[nf], _xf, acc[mf][nf], 0, 0, 0); \
  }                                                                      \
} while (0)

  u16x8 xA[4], xB[4];
  LOADX1(xA, 0);
  SCHED_PIN();
  STAGEW1(0);
  for (int t = 0; t < NS1 - 2; t += 2) {
    LOADX1(xB, (t + 1) * BKW);
    SCHED_PIN();
    STAGEW1(1);
    VMC(8); BAR(); FENCE();
    COMP1(0, xA);
    FENCE(); BAR();
    LOADX1(xA, (t + 2) * BKW);
    SCHED_PIN();
    STAGEW1(0);
    VMC(8); BAR(); FENCE();
    COMP1(1, xB);
    FENCE(); BAR();
  }
  LOADX1(xB, (NS1 - 1) * BKW);
  SCHED_PIN();
  STAGEW1(1);
  VMC(8); BAR(); FENCE();
  COMP1(0, xA);
  FENCE(); BAR();
  VMC(0); BAR(); FENCE();
  COMP1(1, xB);

  // D: row(n) = (lane>>4)*4 + reg, col(token) = lane&15
  const int q = lane >> 4, l15 = lane & 15;
#pragma unroll
  for (int mf = 0; mf < 4; ++mf) {
    const int m = m0 + mf * 16 + l15;
    if (m < cnt) {
#pragma unroll
      for (int nf = 0; nf < 4; ++nf) {
        unsigned short o[4];
#pragma unroll
        for (int r = 0; r < 4; ++r) o[r] = f2bf(acc[mf][nf][r]);
        uint2 pk;
        pk.x = (unsigned)o[0] | ((unsigned)o[1] << 16);
        pk.y = (unsigned)o[2] | ((unsigned)o[3] << 16);
        const int col = colout + w * 64 + nf * 16 + q * 4;
        *(uint2*)&OUT[(size_t)(roff + m) * (2 * I_DIM) + col] = pk;
      }
    }
  }
}

// ---------------- combine: act = silu(raw[:, :I]) * raw[:, I:] ----------------
__global__ __launch_bounds__(256) void combine_kernel(
    const unsigned short* __restrict__ raw_r, const unsigned short* __restrict__ raw_s,
    unsigned short* __restrict__ a_r, unsigned short* __restrict__ a_s)
{
  const int row = blockIdx.x;
  const unsigned short* raw = blockIdx.y ? raw_s : raw_r;
  unsigned short* dst = blockIdx.y ? a_s : a_r;
#pragma unroll
  for (int it = 0; it < 2; ++it) {
    const int i = it * 2048 + threadIdx.x * 8;
    const u16x8 g = *(const u16x8*)&raw[(size_t)row * (2 * I_DIM) + i];
    const u16x8 u = *(const u16x8*)&raw[(size_t)row * (2 * I_DIM) + I_DIM + i];
    u16x8 o;
#pragma unroll
    for (int j = 0; j < 8; ++j) {
      const float gf = bf2f(g[j]);
      const float uf = bf2f(u[j]);
      o[j] = f2bf(gf / (1.f + __expf(-gf)) * uf);
    }
    *(u16x8*)&dst[(size_t)row * I_DIM + i] = o;
  }
}

// ================= GEMM2-wide: out[t] (+)= act @ Wd =================
__global__ __launch_bounds__(256, 2) void gemm2w_kernel(
    const unsigned short* __restrict__ ACT, const float* __restrict__ wd_base,
    float* __restrict__ OUT, const int* __restrict__ counts,
    const int* __restrict__ offsets, const int* __restrict__ perm,
    const int accumulate)
{
  const int e = blockIdx.z;
  const int cnt = counts ? counts[e] : NT;
  const int roff = offsets ? offsets[e] : 0;
  const int m0 = blockIdx.x * BM2;
  if (m0 >= cnt) return;
  const int y = blockIdx.y;
  const float* Wb = wd_base + (size_t)e * I_DIM * H_DIM + y * BN1;

  __shared__ char wl[65536];

  const int lane = threadIdx.x & 63, w = threadIdx.x >> 6;

  const float* wp[8];
#pragma unroll
  for (int s = 0; s < 8; ++s)
    wp[s] = Wb + (size_t)(8 * w + s) * H_DIM + ((lane ^ (w << 2)) << 2);

#define STAGEW2(CUR) do {                                                \
  _Pragma("unroll")                                                      \
  for (int s = 0; s < 8; ++s) {                                          \
    gl2lds16(wp[s], wl + (CUR) * 32768 + (8 * w + s) * 1024);            \
    wp[s] += (size_t)BKW * H_DIM;                                        \
  }                                                                      \
} while (0)

  const unsigned short* xp[2];
#pragma unroll
  for (int mf = 0; mf < 2; ++mf) {
    const int m = m0 + mf * 16 + (lane & 15);
    xp[mf] = ACT + (size_t)(m < cnt ? roff + m : roff) * I_DIM + ((lane >> 4) * 8);
  }
#define LOADX2(XR, K0) do {                                              \
  _Pragma("unroll")                                                      \
  for (int mf = 0; mf < 2; ++mf) XR[mf] = *(const u16x8*)(xp[mf] + (K0));\
} while (0)

  int rb[4];
#pragma unroll
  for (int nf = 0; nf < 4; ++nf)
    rb[nf] = ((lane >> 4) * 8) * 1024 +
             (((w * 64 + nf * 16 + (lane & 15)) * 4) ^ ((lane >> 4) << 6));

  f32x4 acc[2][4] = {};

#define COMP2(CUR, XR) do {                                              \
  const char* _wb = wl + (CUR) * 32768;                                  \
  bf16x8 _af[4];                                                         \
  _Pragma("unroll")                                                      \
  for (int nf = 0; nf < 4; ++nf) {                                       \
    _Pragma("unroll")                                                    \
    for (int j = 0; j < 8; ++j)                                          \
      _af[nf][j] = (__bf16)(*(const float*)(_wb + rb[nf] + j * 1024));   \
  }                                                                      \
  _Pragma("unroll")                                                      \
  for (int mf = 0; mf < 2; ++mf) {                                       \
    const bf16x8 _xf = __builtin_bit_cast(bf16x8, XR[mf]);               \
    _Pragma("unroll")                                                    \
    for (int nf = 0; nf < 4; ++nf)                                       \
      acc[mf][nf] = __builtin_amdgcn_mfma_f32_16x16x32_bf16(_af[nf], _xf, acc[mf][nf], 0, 0, 0); \
  }                                                                      \
} while (0)

  u16x8 xA[2], xB[2];
  LOADX2(xA, 0);
  SCHED_PIN();
  STAGEW2(0);
  for (int t = 0; t < NS2 - 2; t += 2) {
    LOADX2(xB, (t + 1) * BKW);
    SCHED_PIN();
    STAGEW2(1);
    VMC(8); BAR(); FENCE();
    COMP2(0, xA);
    FENCE(); BAR();
    LOADX2(xA, (t + 2) * BKW);
    SCHED_PIN();
    STAGEW2(0);
    VMC(8); BAR(); FENCE();
    COMP2(1, xB);
    FENCE(); BAR();
  }
  LOADX2(xB, (NS2 - 1) * BKW);
  SCHED_PIN();
  STAGEW2(1);
  VMC(8); BAR(); FENCE();
  COMP2(0, xA);
  FENCE(); BAR();
  VMC(0); BAR(); FENCE();
  COMP2(1, xB);

  const int q = lane >> 4, l15 = lane & 15;
#pragma unroll
  for (int mf = 0; mf < 2; ++mf) {
    const int m = m0 + mf * 16 + l15;
    if (m < cnt) {
      const int t = perm ? perm[roff + m] : m;
#pragma unroll
      for (int nf = 0; nf < 4; ++nf) {
        const int col = y * BN1 + w * 64 + nf * 16 + q * 4;
        float* orow = OUT + (size_t)t * H_DIM + col;
        f32x4 v = acc[mf][nf];
        if (accumulate) {
          const f32x4 old = *(const f32x4*)orow;
          v += old;
        }
        *(f32x4*)orow = v;
      }
    }
  }
}

extern "C" void kernel_launch(void* const* d_in, const int* in_sizes, int n_in,
                              void* d_out, int out_size, void* d_ws, size_t ws_size,
                              hipStream_t stream)
{
  const float* x   = (const float*)d_in[0];
  const float* rw  = (const float*)d_in[1];
  const float* gup = (const float*)d_in[2];
  const float* dwn = (const float*)d_in[3];
  const float* sgw = (const float*)d_in[4];
  const float* suw = (const float*)d_in[5];
  const float* sdw = (const float*)d_in[6];
  float* out = (float*)d_out;
  float* rs_out = out + (size_t)NT * H_DIM;   // router_scores [E][T] after out [T][H]

  char* ws = (char*)d_ws;
  int* counts    = (int*)ws;               // 32 B
  int* cursor    = (int*)(ws + 32);        // 32 B
  int* offsets   = (int*)(ws + 64);        // 32 B
  int* expert_of = (int*)(ws + 128);       // 4 KB
  float* score_of = (float*)(ws + 128 + 4096);
  int* perm      = (int*)(ws + 128 + 8192);
  unsigned short* xb    = (unsigned short*)(ws + 16384);        // [T][H]  bf16 (4 MB)
  unsigned short* xs    = xb + (size_t)NT * H_DIM;              // [T][H]  bf16 (4 MB)
  unsigned short* act_r = xs + (size_t)NT * H_DIM;              // [T][I]  bf16 (8 MB)
  unsigned short* act_s = act_r + (size_t)NT * I_DIM;           // [T][I]  bf16 (8 MB)
  unsigned short* raw_r = act_s + (size_t)NT * I_DIM;           // [T][2I] bf16 (16 MB)
  unsigned short* raw_s = raw_r + (size_t)NT * 2 * I_DIM;       // [T][2I] bf16 (16 MB)

  hipMemsetAsync(counts, 0, 64, stream);
  router_kernel<<<dim3(NT / 4), dim3(256), 0, stream>>>(x, rw, rs_out, expert_of, score_of, counts);
  offsets_kernel<<<dim3(1), dim3(64), 0, stream>>>(counts, offsets, cursor);
  scatter_kernel<<<dim3(NT / 256), dim3(256), 0, stream>>>(expert_of, offsets, cursor, perm);
  gather_kernel<<<dim3(NT), dim3(256), 0, stream>>>(x, perm, score_of, xb, xs);

  gemm1w_kernel<<<dim3(NT / BM1, 32, NE + 1), dim3(256), 0, stream>>>(
      xs, xb, gup, sgw, suw, raw_r, raw_s, counts, offsets);
  combine_kernel<<<dim3(NT, 2), dim3(256), 0, stream>>>(raw_r, raw_s, act_r, act_s);
  gemm2w_kernel<<<dim3(NT / BM2, H_DIM / BN1, 1), dim3(256), 0, stream>>>(
      act_s, sdw, out, nullptr, nullptr, nullptr, 0);
  gemm2w_kernel<<<dim3(NT / BM2, H_DIM / BN1, NE), dim3(256), 0, stream>>>(
      act_r, dwn, out, counts, offsets, perm, 1);
}

// Round 11
// 1077.615 us; speedup vs baseline: 1.6620x; 1.6620x over previous
//
#include <hip/hip_runtime.h>
#include <hip/hip_bf16.h>

#define H_DIM 2048
#define I_DIM 4096
#define NE 8
#define NT 1024

#define BM 128
#define BN 64
#define BK 32
#define NS1 (H_DIM / BK)   // 64
#define NS2 (I_DIM / BK)   // 128

typedef __bf16 bf16x8 __attribute__((ext_vector_type(8)));
typedef float f32x4 __attribute__((ext_vector_type(4)));
typedef unsigned short u16x8 __attribute__((ext_vector_type(8)));

__device__ __forceinline__ unsigned short f2bf(float f) {
  return __builtin_bit_cast(unsigned short, (__bf16)f);
}

// async global->LDS, 16B per lane; LDS dest = wave-uniform base + lane*16
__device__ __forceinline__ void gl2lds16(const void* g, void* l) {
  __builtin_amdgcn_global_load_lds(
      (const __attribute__((address_space(1))) unsigned int*)g,
      (__attribute__((address_space(3))) unsigned int*)l, 16, 0, 0);
}

#define FENCE() asm volatile("" ::: "memory")
#define BAR() __builtin_amdgcn_s_barrier()
#define VMC(N) asm volatile("s_waitcnt vmcnt(" #N ")" ::: "memory")

// ---------------- weight convert: fp32 -> bf16, same layout ----------------
__global__ __launch_bounds__(256) void convert_kernel(
    const float* __restrict__ src, unsigned short* __restrict__ dst, int n8)
{
  int i = blockIdx.x * 256 + threadIdx.x;
  const int stride = gridDim.x * 256;
  for (; i < n8; i += stride) {
    const f32x4 a = ((const f32x4*)src)[2 * (size_t)i];
    const f32x4 b = ((const f32x4*)src)[2 * (size_t)i + 1];
    u16x8 o;
#pragma unroll
    for (int j = 0; j < 4; ++j) { o[j] = f2bf(a[j]); o[4 + j] = f2bf(b[j]); }
    ((u16x8*)dst)[i] = o;
  }
}

// ---------------- router: 1 wave per token ----------------
__global__ __launch_bounds__(256) void router_kernel(
    const float* __restrict__ x, const float* __restrict__ rw,
    float* __restrict__ rs_out, int* __restrict__ expert_of,
    float* __restrict__ score_of, int* __restrict__ counts)
{
  const int lane = threadIdx.x & 63;
  const int wv = threadIdx.x >> 6;
  const int t = blockIdx.x * 4 + wv;
  float acc[NE];
#pragma unroll
  for (int e = 0; e < NE; ++e) acc[e] = 0.f;
  const float* xr = x + (size_t)t * H_DIM;
  for (int h0 = 0; h0 < H_DIM; h0 += 64) {
    const float xv = xr[h0 + lane];
    const float* rwp = rw + (size_t)(h0 + lane) * NE;
    const f32x4 r0 = *(const f32x4*)rwp;
    const f32x4 r1 = *(const f32x4*)(rwp + 4);
#pragma unroll
    for (int e = 0; e < 4; ++e) { acc[e] += xv * r0[e]; acc[e + 4] += xv * r1[e]; }
  }
#pragma unroll
  for (int e = 0; e < NE; ++e) {
    acc[e] += __shfl_xor(acc[e], 32, 64);
    acc[e] += __shfl_xor(acc[e], 16, 64);
    acc[e] += __shfl_xor(acc[e], 8, 64);
    acc[e] += __shfl_xor(acc[e], 4, 64);
    acc[e] += __shfl_xor(acc[e], 2, 64);
    acc[e] += __shfl_xor(acc[e], 1, 64);
  }
  int best = 0; float bv = acc[0];
#pragma unroll
  for (int e = 1; e < NE; ++e) if (acc[e] > bv) { bv = acc[e]; best = e; }
  const float score = 1.f / (1.f + __expf(-bv));
  if (lane < NE) rs_out[(size_t)lane * NT + t] = (lane == best) ? score : 0.f;
  if (lane == 0) {
    expert_of[t] = best;
    score_of[t] = score;
    atomicAdd(&counts[best], 1);
  }
}

// ---------------- offsets ----------------
__global__ void offsets_kernel(const int* __restrict__ counts,
                               int* __restrict__ offsets, int* __restrict__ cursor)
{
  if (threadIdx.x == 0) {
    int run = 0;
#pragma unroll
    for (int e = 0; e < NE; ++e) { offsets[e] = run; run += counts[e]; cursor[e] = 0; }
  }
}

// ---------------- scatter ----------------
__global__ void scatter_kernel(const int* __restrict__ expert_of,
                               const int* __restrict__ offsets,
                               int* __restrict__ cursor, int* __restrict__ perm)
{
  const int t = blockIdx.x * 256 + threadIdx.x;
  const int e = expert_of[t];
  const int p = atomicAdd(&cursor[e], 1);
  perm[offsets[e] + p] = t;
}

// ---------------- gather ----------------
__global__ __launch_bounds__(256) void gather_kernel(
    const float* __restrict__ x, const int* __restrict__ perm,
    const float* __restrict__ score_of, unsigned short* __restrict__ xb,
    unsigned short* __restrict__ xs)
{
  const int b = blockIdx.x;
  const int c = threadIdx.x * 8;
  const int src = perm[b];
  const float s = score_of[src];
  const float* xrow = x + (size_t)b * H_DIM + c;
  const float* srow = x + (size_t)src * H_DIM + c;
  u16x8 vb, vs;
#pragma unroll
  for (int j = 0; j < 8; ++j) {
    vb[j] = f2bf(xrow[j]);
    vs[j] = f2bf(srow[j] * s);
  }
  *(u16x8*)&xb[(size_t)b * H_DIM + c] = vb;
  *(u16x8*)&xs[(size_t)b * H_DIM + c] = vs;
}

// ================= GEMM1: act = silu(X@Wg) * (X@Wu)  (bf16 W) =================
// X LDS tile [128][32] bf16 (8KB), chunk-swz c^((m>>1)&3), b128 reads (proven r8).
// W LDS tile [32][64] bf16 (4KB), byte-swz k*128 + ((n*2)^((k>>3&3)<<5)):
//   reads conflict-free; gl2lds source pre-swizzled with the same involution.
// 3-buffer ring, stage 2 tiles ahead, vmcnt(8) steady (4 loads/wave/tile).
// Per-block K-ring start offset de-synchronizes the grid.
__global__ __launch_bounds__(256) void gemm1_kernel(
    const unsigned short* __restrict__ xs, const unsigned short* __restrict__ xb,
    const unsigned short* __restrict__ gupb, const unsigned short* __restrict__ sgwb,
    const unsigned short* __restrict__ suwb, unsigned short* __restrict__ act_r,
    unsigned short* __restrict__ act_s, const int* __restrict__ counts,
    const int* __restrict__ offsets)
{
  const int e = blockIdx.z;
  int cnt, roff; size_t ldw;
  const unsigned short* X; const unsigned short* Wg; const unsigned short* Wu;
  unsigned short* OUT;
  if (e < NE) {
    cnt = counts[e]; roff = offsets[e]; ldw = 2 * I_DIM;
    X = xs; Wg = gupb + (size_t)e * H_DIM * 2 * I_DIM; Wu = Wg + I_DIM; OUT = act_r;
  } else {
    cnt = NT; roff = 0; ldw = I_DIM;
    X = xb; Wg = sgwb; Wu = suwb; OUT = act_s;
  }
  const int m0 = blockIdx.x * BM;
  if (m0 >= cnt) return;
  const int n0 = blockIdx.y * BN;

  __shared__ char lds[49152];
  char* const xl  = lds;            // [3][8192]
  char* const wgl = lds + 24576;    // [3][4096]
  char* const wul = lds + 36864;    // [3][4096]

  const int lane = threadIdx.x & 63, w = threadIdx.x >> 6;

  // X slots: wave w stages rows 32w..32w+31 (2 x 1KB)
  const unsigned short* spx[2]; int dx[2];
#pragma unroll
  for (int s = 0; s < 2; ++s) {
    const int g = w * 2 + s;
    const int m = 16 * g + (lane >> 2);
    const int c = lane & 3;
    const int msrc = (m0 + m < cnt) ? (roff + m0 + m) : roff;
    spx[s] = X + (size_t)msrc * H_DIM + ((c ^ ((m >> 1) & 3)) << 3);
    dx[s] = g * 1024;
  }
  // W slots: wave w stages rows 8w..8w+7 of the [32][64] tile (1KB each)
  const int wr = 8 * w + (lane >> 3);
  const int wc = (lane & 7) ^ ((w & 3) << 1);
  const unsigned short* spg = Wg + (size_t)wr * ldw + n0 + (wc << 3);
  const unsigned short* spu = Wu + (size_t)wr * ldw + n0 + (wc << 3);
  const int dw = w * 1024;

#define STAGE1(BUF, POS) do {                                            \
  const size_t _xo = (size_t)(POS) * BK;                                 \
  const size_t _wo = (size_t)(POS) * BK * ldw;                           \
  gl2lds16(spx[0] + _xo, xl + (BUF) * 8192 + dx[0]);                     \
  gl2lds16(spx[1] + _xo, xl + (BUF) * 8192 + dx[1]);                     \
  gl2lds16(spg + _wo, wgl + (BUF) * 4096 + dw);                          \
  gl2lds16(spu + _wo, wul + (BUF) * 4096 + dw);                          \
} while (0)

  const int q = lane >> 4, l15 = lane & 15;
  const int xro = l15 * 64 + ((q ^ ((l15 >> 1) & 3)) << 4);
  // W read offsets: j -> byte (q*8+j)*128 + ((n_loc*2) ^ (q<<5))
  const int wbase = (q * 8) * 128 + (((w * 16 + l15) * 2) ^ (q << 5));

  f32x4 accg[8] = {};
  f32x4 accu[8] = {};

#define COMP1(BUF) do {                                                  \
  const char* _xb = xl + (BUF) * 8192 + xro;                             \
  const char* _wg = wgl + (BUF) * 4096 + wbase;                          \
  const char* _wu = wul + (BUF) * 4096 + wbase;                          \
  u16x8 _gb, _ub;                                                        \
  _Pragma("unroll")                                                      \
  for (int j = 0; j < 8; ++j) {                                          \
    _gb[j] = *(const unsigned short*)(_wg + j * 128);                    \
    _ub[j] = *(const unsigned short*)(_wu + j * 128);                    \
  }                                                                      \
  const bf16x8 _gf = __builtin_bit_cast(bf16x8, _gb);                    \
  const bf16x8 _uf = __builtin_bit_cast(bf16x8, _ub);                    \
  _Pragma("unroll")                                                      \
  for (int mb = 0; mb < 8; ++mb) {                                       \
    const u16x8 _xr = *(const u16x8*)(_xb + mb * 1024);                  \
    const bf16x8 _xf = __builtin_bit_cast(bf16x8, _xr);                  \
    accg[mb] = __builtin_amdgcn_mfma_f32_16x16x32_bf16(_gf, _xf, accg[mb], 0, 0, 0); \
    accu[mb] = __builtin_amdgcn_mfma_f32_16x16x32_bf16(_uf, _xf, accu[mb], 0, 0, 0); \
  }                                                                      \
} while (0)

  const int k0s = (blockIdx.x * 17 + blockIdx.y * 5 + blockIdx.z * 23) & (NS1 - 1);
  {
    int p1 = k0s + 1; if (p1 >= NS1) p1 -= NS1;
    STAGE1(0, k0s);
    STAGE1(1, p1);
  }
  for (int t = 0; t < NS1; ++t) {
    if (t + 2 < NS1) {
      int p = k0s + t + 2; if (p >= NS1) p -= NS1;
      STAGE1((t + 2) % 3, p);
      VMC(8);
    } else if (t + 2 == NS1) {
      VMC(4);
    } else {
      VMC(0);
    }
    BAR(); FENCE();
    COMP1(t % 3);
    FENCE(); BAR();
  }

  // D layout: row(n) = (lane>>4)*4 + reg, col(m) = lane&15
  const int nw = n0 + w * 16 + (q * 4);
#pragma unroll
  for (int mb = 0; mb < 8; ++mb) {
    const int m = m0 + mb * 16 + l15;
    if (m < cnt) {
      unsigned short o[4];
#pragma unroll
      for (int r = 0; r < 4; ++r) {
        const float g = accg[mb][r];
        const float u = accu[mb][r];
        const float sg = g / (1.f + __expf(-g));
        o[r] = f2bf(sg * u);
      }
      uint2 pk;
      pk.x = (unsigned)o[0] | ((unsigned)o[1] << 16);
      pk.y = (unsigned)o[2] | ((unsigned)o[3] << 16);
      *(uint2*)&OUT[(size_t)(roff + m) * I_DIM + nw] = pk;
    }
  }
}

// ================= GEMM2: out[t] (+)= act @ Wd  (bf16 Wd) =================
__global__ __launch_bounds__(256) void gemm2_kernel(
    const unsigned short* __restrict__ ACT, const unsigned short* __restrict__ wd_base,
    float* __restrict__ OUT, const int* __restrict__ counts,
    const int* __restrict__ offsets, const int* __restrict__ perm,
    const int accumulate)
{
  const int e = blockIdx.z;
  const int cnt = counts ? counts[e] : NT;
  const int roff = offsets ? offsets[e] : 0;
  const int m0 = blockIdx.x * BM;
  if (m0 >= cnt) return;
  const int n0 = blockIdx.y * BN;
  const unsigned short* Wd = wd_base + (size_t)e * I_DIM * H_DIM;

  __shared__ char lds[36864];
  char* const xl  = lds;            // [3][8192]
  char* const wdl = lds + 24576;    // [3][4096]

  const int lane = threadIdx.x & 63, w = threadIdx.x >> 6;

  const unsigned short* spx[2]; int dx[2];
#pragma unroll
  for (int s = 0; s < 2; ++s) {
    const int g = w * 2 + s;
    const int m = 16 * g + (lane >> 2);
    const int c = lane & 3;
    const int msrc = (m0 + m < cnt) ? (roff + m0 + m) : roff;
    spx[s] = ACT + (size_t)msrc * I_DIM + ((c ^ ((m >> 1) & 3)) << 3);
    dx[s] = g * 1024;
  }
  const int wr = 8 * w + (lane >> 3);
  const int wc = (lane & 7) ^ ((w & 3) << 1);
  const unsigned short* spw = Wd + (size_t)wr * H_DIM + n0 + (wc << 3);
  const int dw = w * 1024;

#define STAGE2(BUF, POS) do {                                            \
  const size_t _xo = (size_t)(POS) * BK;                                 \
  const size_t _wo = (size_t)(POS) * BK * H_DIM;                         \
  gl2lds16(spx[0] + _xo, xl + (BUF) * 8192 + dx[0]);                     \
  gl2lds16(spx[1] + _xo, xl + (BUF) * 8192 + dx[1]);                     \
  gl2lds16(spw + _wo, wdl + (BUF) * 4096 + dw);                          \
} while (0)

  const int q = lane >> 4, l15 = lane & 15;
  const int xro = l15 * 64 + ((q ^ ((l15 >> 1) & 3)) << 4);
  const int wbase = (q * 8) * 128 + (((w * 16 + l15) * 2) ^ (q << 5));

  f32x4 acc[8] = {};

#define COMP2(BUF) do {                                                  \
  const char* _xb = xl + (BUF) * 8192 + xro;                             \
  const char* _wd = wdl + (BUF) * 4096 + wbase;                          \
  u16x8 _db;                                                             \
  _Pragma("unroll")                                                      \
  for (int j = 0; j < 8; ++j)                                            \
    _db[j] = *(const unsigned short*)(_wd + j * 128);                    \
  const bf16x8 _df = __builtin_bit_cast(bf16x8, _db);                    \
  _Pragma("unroll")                                                      \
  for (int mb = 0; mb < 8; ++mb) {                                       \
    const u16x8 _xr = *(const u16x8*)(_xb + mb * 1024);                  \
    const bf16x8 _xf = __builtin_bit_cast(bf16x8, _xr);                  \
    acc[mb] = __builtin_amdgcn_mfma_f32_16x16x32_bf16(_df, _xf, acc[mb], 0, 0, 0); \
  }                                                                      \
} while (0)

  const int k0s = (blockIdx.x * 29 + blockIdx.y * 11 + blockIdx.z * 37) & (NS2 - 1);
  {
    int p1 = k0s + 1; if (p1 >= NS2) p1 -= NS2;
    STAGE2(0, k0s);
    STAGE2(1, p1);
  }
  for (int t = 0; t < NS2; ++t) {
    if (t + 2 < NS2) {
      int p = k0s + t + 2; if (p >= NS2) p -= NS2;
      STAGE2((t + 2) % 3, p);
      VMC(6);
    } else if (t + 2 == NS2) {
      VMC(3);
    } else {
      VMC(0);
    }
    BAR(); FENCE();
    COMP2(t % 3);
    FENCE(); BAR();
  }

  const int nw = n0 + w * 16 + (q * 4);
#pragma unroll
  for (int mb = 0; mb < 8; ++mb) {
    const int m = m0 + mb * 16 + l15;
    if (m < cnt) {
      const int t = perm ? perm[roff + m] : m;
      float* orow = OUT + (size_t)t * H_DIM + nw;
      f32x4 v = acc[mb];
      if (accumulate) {
        const f32x4 old = *(const f32x4*)orow;
        v += old;
      }
      *(f32x4*)orow = v;
    }
  }
}

extern "C" void kernel_launch(void* const* d_in, const int* in_sizes, int n_in,
                              void* d_out, int out_size, void* d_ws, size_t ws_size,
                              hipStream_t stream)
{
  const float* x   = (const float*)d_in[0];
  const float* rw  = (const float*)d_in[1];
  const float* gup = (const float*)d_in[2];
  const float* dwn = (const float*)d_in[3];
  const float* sgw = (const float*)d_in[4];
  const float* suw = (const float*)d_in[5];
  const float* sdw = (const float*)d_in[6];
  float* out = (float*)d_out;
  float* rs_out = out + (size_t)NT * H_DIM;   // router_scores [E][T] after out [T][H]

  char* ws = (char*)d_ws;
  int* counts    = (int*)ws;               // 32 B
  int* cursor    = (int*)(ws + 32);        // 32 B
  int* offsets   = (int*)(ws + 64);        // 32 B
  int* expert_of = (int*)(ws + 128);       // 4 KB
  float* score_of = (float*)(ws + 128 + 4096);
  int* perm      = (int*)(ws + 128 + 8192);
  unsigned short* xb    = (unsigned short*)(ws + 16384);        // [T][H]  bf16 (4 MB)
  unsigned short* xs    = xb + (size_t)NT * H_DIM;              // [T][H]  bf16 (4 MB)
  unsigned short* act_r = xs + (size_t)NT * H_DIM;              // [T][I]  bf16 (8 MB)
  unsigned short* act_s = act_r + (size_t)NT * I_DIM;           // [T][I]  bf16 (8 MB)
  unsigned short* gupb  = act_s + (size_t)NT * I_DIM;           // 256 MB
  unsigned short* dwnb  = gupb + (size_t)NE * H_DIM * 2 * I_DIM; // 128 MB
  unsigned short* sgwb  = dwnb + (size_t)NE * I_DIM * H_DIM;    // 16 MB
  unsigned short* suwb  = sgwb + (size_t)H_DIM * I_DIM;         // 16 MB
  unsigned short* sdwb  = suwb + (size_t)H_DIM * I_DIM;         // 16 MB

  const int n8_gup = NE * H_DIM * 2 * I_DIM / 8;
  const int n8_dwn = NE * I_DIM * H_DIM / 8;
  const int n8_sh  = H_DIM * I_DIM / 8;

  hipMemsetAsync(counts, 0, 64, stream);
  convert_kernel<<<dim3(8192), dim3(256), 0, stream>>>(gup, gupb, n8_gup);
  convert_kernel<<<dim3(8192), dim3(256), 0, stream>>>(dwn, dwnb, n8_dwn);
  convert_kernel<<<dim3(4096), dim3(256), 0, stream>>>(sgw, sgwb, n8_sh);
  convert_kernel<<<dim3(4096), dim3(256), 0, stream>>>(suw, suwb, n8_sh);
  convert_kernel<<<dim3(4096), dim3(256), 0, stream>>>(sdw, sdwb, n8_sh);

  router_kernel<<<dim3(NT / 4), dim3(256), 0, stream>>>(x, rw, rs_out, expert_of, score_of, counts);
  offsets_kernel<<<dim3(1), dim3(64), 0, stream>>>(counts, offsets, cursor);
  scatter_kernel<<<dim3(NT / 256), dim3(256), 0, stream>>>(expert_of, offsets, cursor, perm);
  gather_kernel<<<dim3(NT), dim3(256), 0, stream>>>(x, perm, score_of, xb, xs);

  gemm1_kernel<<<dim3(NT / BM, I_DIM / BN, NE + 1), dim3(256), 0, stream>>>(
      xs, xb, gupb, sgwb, suwb, act_r, act_s, counts, offsets);
  gemm2_kernel<<<dim3(NT / BM, H_DIM / BN, 1), dim3(256), 0, stream>>>(
      act_s, sdwb, out, nullptr, nullptr, nullptr, 0);
  gemm2_kernel<<<dim3(NT / BM, H_DIM / BN, NE), dim3(256), 0, stream>>>(
      act_r, dwnb, out, counts, offsets, perm, 1);
}